// Round 9
// baseline (196.650 us; speedup 1.0000x reference)
//
#include <hip/hip_runtime.h>

#define BB 4
#define NN 512
#define FIN 128
#define HH 4
#define DD 32
#define HID 128
#define NOUT 384   // 128 src + 128 tgt + 128 res
#define MT 8
#define LN_EPS 1e-5f
#define NEG 0.2f
#define SCALE 0.17677669529663687f

typedef __attribute__((ext_vector_type(8))) short bf16x8;
typedef __attribute__((ext_vector_type(4))) float f32x4;

__device__ __forceinline__ float leaky(float x){ return x > 0.f ? x : NEG*x; }

// round-to-nearest-even fp32 -> bf16 (finite inputs)
__device__ __forceinline__ unsigned f2bf(float f){
    unsigned u = __float_as_uint(f);
    return (u + 0x7fffu + ((u >> 16) & 1u)) >> 16;
}
__device__ __forceinline__ float bflo(unsigned u){ return __uint_as_float(u << 16); }
__device__ __forceinline__ float bfhi(unsigned u){ return __uint_as_float(u & 0xffff0000u); }

// Pack Wt[k][o]: o in [0,128)=W_src rows, [128,256)=W_tgt rows, [256,384)=W_res rows
__global__ void pack_w(const float* __restrict__ Wsrc, const float* __restrict__ Wtgt,
                       const float* __restrict__ Wres, float* __restrict__ Wt) {
    int idx = blockIdx.x * 256 + threadIdx.x;
    if (idx >= FIN * NOUT) return;
    int k = idx / NOUT, o = idx % NOUT;
    float v;
    if (o < 128)      v = Wsrc[o * FIN + k];
    else if (o < 256) v = Wtgt[(o - 128) * FIN + k];
    else              v = Wres[(o - 256) * FIN + k];
    Wt[idx] = v;
}

// Fused proj: Linear -> LayerNorm(32) -> LeakyReLU for src/tgt, Linear+bias+Leaky for res.
// U_tgt emitted ONLY as bf16, twice: tT[bh][d][n] (agg B-operand) and
// tP[bh][d2][n] (escore t-columns, d-pairs packed in u32).
__global__ __launch_bounds__(NOUT) void proj_kernel(
    const float* __restrict__ x, const float* __restrict__ Wt,
    const float* __restrict__ gsrc, const float* __restrict__ bsrc,
    const float* __restrict__ gtgt, const float* __restrict__ btgt,
    const float* __restrict__ bres,
    float* __restrict__ Usrc, float* __restrict__ res,
    unsigned short* __restrict__ tT, unsigned* __restrict__ tP)
{
    __shared__ float xs[MT * FIN];
    int tid = threadIdx.x;
    int r0 = blockIdx.x * MT;              // row over flattened [B*N]
    const float* base = x + (size_t)r0 * FIN;
    for (int idx = tid; idx < MT * FIN; idx += NOUT) xs[idx] = base[idx];
    __syncthreads();

    int o = tid;
    float acc[MT];
    #pragma unroll
    for (int m = 0; m < MT; m++) acc[m] = 0.f;
    for (int k = 0; k < FIN; k++) {
        float w = Wt[k * NOUT + o];
        #pragma unroll
        for (int m = 0; m < MT; m++) acc[m] = fmaf(w, xs[m * FIN + k], acc[m]);
    }

    float gg = 1.f, bb2 = 0.f, bres_v = 0.f;
    if (o < 128)      { gg = gsrc[o];       bb2 = bsrc[o]; }
    else if (o < 256) { gg = gtgt[o - 128]; bb2 = btgt[o - 128]; }
    else              { bres_v = bres[o - 256]; }

    unsigned bfall[MT];
    unsigned tpack[4];
    #pragma unroll
    for (int m = 0; m < MT; m++) {
        int r = r0 + m;
        int b = r >> 9;            // /512
        int n = r & (NN - 1);
        float v = acc[m];
        if (o < 256) {
            float s = v, sq = v * v;
            #pragma unroll
            for (int msk = 16; msk >= 1; msk >>= 1) {
                s  += __shfl_xor(s,  msk);
                sq += __shfl_xor(sq, msk);
            }
            float mean = s * (1.f / DD);
            float var  = sq * (1.f / DD) - mean * mean;
            float nv = (v - mean) * rsqrtf(var + LN_EPS);
            nv = leaky(nv * gg + bb2);
            int oo = o & 127;
            int hh = oo >> 5, d = oo & 31;
            if (o < 128) {
                Usrc[((size_t)(b * HH + hh) * NN + n) * DD + d] = nv;
            } else {
                unsigned bf = f2bf(nv);
                bfall[m] = bf;
                if (m & 1) tpack[m >> 1] |= bf << 16; else tpack[m >> 1] = bf;
            }
        } else {
            res[(size_t)r * HID + (o - 256)] = leaky(v + bres_v);
        }
    }
    if (o >= 128 && o < 256) {
        int oo = o & 127, hh = oo >> 5, d = oo & 31;
        int b = r0 >> 9, n0 = r0 & (NN - 1);
        size_t off = ((size_t)(b * HH + hh) * DD + d) * NN + n0;   // n0 % 8 == 0
        *(uint4*)(tT + off) = make_uint4(tpack[0], tpack[1], tpack[2], tpack[3]);
        // d-pair packing for escore: lanes d, d^1 are adjacent in the wave
        unsigned pd[MT];
        #pragma unroll
        for (int m = 0; m < MT; m++) {
            unsigned prt = (unsigned)__shfl_xor((int)bfall[m], 1);
            pd[m] = bfall[m] | (prt << 16);          // valid on even-d lanes
        }
        if ((d & 1) == 0) {
            size_t offp = ((size_t)(b * HH + hh) * 16 + (d >> 1)) * NN + n0;
            *(uint4*)(tP + offp)     = make_uint4(pd[0], pd[1], pd[2], pd[3]);
            *(uint4*)(tP + offp + 4) = make_uint4(pd[4], pd[5], pd[6], pd[7]);
        }
    }
}

// e+softmax kernel, v3: 256-thread blocks, one j-half per block, 8 i-rows.
// Thread owns one t column (16 packed bf16x2 u32 regs). Writes UNNORMALIZED
// p (bf16) + per-64-j-chunk row sums to rsum[bh][i][8]; agg divides later
// (scale cancels). Row term dropped (softmax shift-inv); no max pass
// (|e| <~ 25, fp32-exp safe). launch_bounds(256,6): VGPR cap 84, 6 blocks/CU.
__global__ __launch_bounds__(256, 6) void escore_kernel(
    const float* __restrict__ Usrc, const unsigned* __restrict__ tP,
    const float* __restrict__ attn, unsigned short* __restrict__ pOut,
    float* __restrict__ rsum)
{
    __shared__ float s_lds[8][DD];     // 1KB

    const int tid = threadIdx.x;
    const int blk = blockIdx.x;        // grid 2048: bh(4b) | it(6b) | jh(1b)
    const int jh = blk & 1;
    const int it = (blk >> 1) & 63;
    const int bh = blk >> 7;

    const int j = jh * 256 + tid;
    const unsigned* tcol = tP + (size_t)bh * 16 * NN + j;     // coalesced u32 cols
    const float* srcU = Usrc + (size_t)bh * NN * DD + (size_t)(it * 8) * DD;
    const float* aU   = attn + (bh & 3) * DD;                 // uniform -> s_load

    unsigned tpk[16];
    #pragma unroll
    for (int d2 = 0; d2 < 16; d2++) tpk[d2] = tcol[d2 * NN];

    if (tid < 64) ((float4*)s_lds)[tid] = ((const float4*)srcU)[tid];
    __syncthreads();

    float At = 0.f, acc[8];
    #pragma unroll
    for (int r = 0; r < 8; r++) acc[r] = 0.f;

    #pragma unroll
    for (int dg = 0; dg < 8; dg++) {                // quad of d = [4dg, 4dg+4)
        const float a0 = aU[dg*4+0], a1 = aU[dg*4+1], a2 = aU[dg*4+2], a3 = aU[dg*4+3];
        const float t0 = bflo(tpk[dg*2]),   t1 = bfhi(tpk[dg*2]);
        const float t2 = bflo(tpk[dg*2+1]), t3 = bfhi(tpk[dg*2+1]);
        At = fmaf(a0, t0, fmaf(a1, t1, fmaf(a2, t2, fmaf(a3, t3, At))));
        #pragma unroll
        for (int r = 0; r < 8; r++) {
            float4 sv = *(float4*)&s_lds[r][dg * 4];
            acc[r] = fmaf(a0, fabsf(sv.x + t0), acc[r]);
            acc[r] = fmaf(a1, fabsf(sv.y + t1), acc[r]);
            acc[r] = fmaf(a2, fabsf(sv.z + t2), acc[r]);
            acc[r] = fmaf(a3, fabsf(sv.w + t3), acc[r]);
        }
    }

    const float cAt = 0.6f * SCALE * At;
    const int lane = tid & 63;
    const int chunk = jh * 4 + (tid >> 6);          // j-chunk of 64: 0..7
    unsigned short* pRow = pOut + ((size_t)bh * NN + it * 8) * NN + j;
    float* rs = rsum + ((size_t)bh * NN + it * 8) * 8 + chunk;

    #pragma unroll
    for (int r = 0; r < 8; r++) {
        float p = __expf(fmaf(0.4f * SCALE, acc[r], cAt));   // unnormalized
        float s = p;
        #pragma unroll
        for (int msk = 32; msk >= 1; msk >>= 1) s += __shfl_xor(s, msk);
        if (lane == 0) rs[(size_t)r * 8] = s;
        pRow[(size_t)r * NN] = (unsigned short)f2bf(p);
    }
}

// agg: batched MFMA GEMM  out[bh] = p~[bh] (512x512) @ tT[bh] (32x512, k-contig),
// normalized by rowsum (sum of 8 chunk partials) + residual + ReLU.
__global__ __launch_bounds__(256) void agg_kernel(
    const unsigned short* __restrict__ pM, const unsigned short* __restrict__ tT,
    const float* __restrict__ rsum, const float* __restrict__ res,
    float* __restrict__ out)
{
    const int tid = threadIdx.x, l = tid & 63;
    const int gw = blockIdx.x * 4 + (tid >> 6);   // 0..511
    const int bh = gw >> 5, mt = gw & 31;
    const int b = bh >> 2, h = bh & 3;

    const unsigned short* pA = pM + (size_t)bh * NN * NN
                               + (size_t)(mt * 16 + (l & 15)) * NN + ((l >> 4) * 8);
    const unsigned short* pB = tT + (size_t)bh * DD * NN
                               + (size_t)(l & 15) * NN + ((l >> 4) * 8);

    f32x4 acc0 = {0.f, 0.f, 0.f, 0.f}, acc1 = {0.f, 0.f, 0.f, 0.f};
    #pragma unroll
    for (int kt = 0; kt < 16; kt++) {
        bf16x8 av = *(const bf16x8*)(pA + kt * 32);
        bf16x8 b0 = *(const bf16x8*)(pB + kt * 32);
        bf16x8 b1 = *(const bf16x8*)(pB + 16 * NN + kt * 32);
        acc0 = __builtin_amdgcn_mfma_f32_16x16x32_bf16(av, b0, acc0, 0, 0, 0);
        acc1 = __builtin_amdgcn_mfma_f32_16x16x32_bf16(av, b1, acc1, 0, 0, 0);
    }

    // C/D layout (m89): col = lane&15, row = (lane>>4)*4 + reg
    const int i0 = mt * 16 + (l >> 4) * 4;
    const int cc = l & 15;
    #pragma unroll
    for (int q = 0; q < 4; q++) {
        const int ri = i0 + q;
        const float* rsq = rsum + ((size_t)bh * NN + ri) * 8;
        float4 s0 = *(const float4*)rsq;
        float4 s1 = *(const float4*)(rsq + 4);
        float sum = ((s0.x + s0.y) + (s0.z + s0.w)) + ((s1.x + s1.y) + (s1.z + s1.w));
        float inv = 1.f / sum;
        size_t row = (size_t)b * NN + ri;
        size_t a0 = row * HID + h * DD + cc;
        out[a0]      = fmaxf(fmaf(acc0[q], inv, res[a0]),      0.f);
        out[a0 + 16] = fmaxf(fmaf(acc1[q], inv, res[a0 + 16]), 0.f);
    }
}

extern "C" void kernel_launch(void* const* d_in, const int* in_sizes, int n_in,
                              void* d_out, int out_size, void* d_ws, size_t ws_size,
                              hipStream_t stream) {
    const float* uf   = (const float*)d_in[0];
    const float* Wsrc = (const float*)d_in[1];
    const float* gsrc = (const float*)d_in[2];
    const float* bsrc = (const float*)d_in[3];
    const float* Wtgt = (const float*)d_in[4];
    const float* gtgt = (const float*)d_in[5];
    const float* btgt = (const float*)d_in[6];
    const float* attn = (const float*)d_in[7];
    const float* Wres = (const float*)d_in[8];
    const float* bres = (const float*)d_in[9];
    float* out = (float*)d_out;

    float* ws   = (float*)d_ws;
    float* Wt   = ws;                        // 49152 f
    float* Usrc = ws + 49152;                // 262144 f
    float* resb = Usrc + 262144;             // 262144 f
    unsigned short* tT = (unsigned short*)(resb + 262144);   // 262144 u16
    unsigned* tP = (unsigned*)(tT + 262144);                 // 131072 u32
    float* rsum = (float*)(tP + 131072);                     // 65536 f
    unsigned short* pM = (unsigned short*)(rsum + 65536);    // 16*512*512 u16 = 8 MB

    pack_w<<<(FIN * NOUT + 255) / 256, 256, 0, stream>>>(Wsrc, Wtgt, Wres, Wt);
    proj_kernel<<<(BB * NN) / MT, NOUT, 0, stream>>>(uf, Wt, gsrc, bsrc, gtgt, btgt,
                                                     bres, Usrc, resb, tT, tP);
    escore_kernel<<<BB * HH * (NN / 8) * 2, 256, 0, stream>>>(Usrc, tP, attn, pM, rsum);
    agg_kernel<<<128, 256, 0, stream>>>(pM, tT, rsum, resb, out);
}

// Round 10
// 125.837 us; speedup vs baseline: 1.5627x; 1.5627x over previous
//
#include <hip/hip_runtime.h>

#define BB 4
#define NN 512
#define FIN 128
#define HH 4
#define DD 32
#define HID 128
#define NOUT 384   // 128 src + 128 tgt + 128 res
#define MT 8
#define LN_EPS 1e-5f
#define NEG 0.2f
#define SCALE 0.17677669529663687f

typedef __attribute__((ext_vector_type(8))) short bf16x8;
typedef __attribute__((ext_vector_type(4))) float f32x4;

__device__ __forceinline__ float leaky(float x){ return x > 0.f ? x : NEG*x; }

// round-to-nearest-even fp32 -> bf16 (finite inputs)
__device__ __forceinline__ unsigned f2bf(float f){
    unsigned u = __float_as_uint(f);
    return (u + 0x7fffu + ((u >> 16) & 1u)) >> 16;
}
__device__ __forceinline__ float bflo(unsigned u){ return __uint_as_float(u << 16); }
__device__ __forceinline__ float bfhi(unsigned u){ return __uint_as_float(u & 0xffff0000u); }

// Pack Wt[k][o]: o in [0,128)=W_src rows, [128,256)=W_tgt rows, [256,384)=W_res rows
__global__ void pack_w(const float* __restrict__ Wsrc, const float* __restrict__ Wtgt,
                       const float* __restrict__ Wres, float* __restrict__ Wt) {
    int idx = blockIdx.x * 256 + threadIdx.x;
    if (idx >= FIN * NOUT) return;
    int k = idx / NOUT, o = idx % NOUT;
    float v;
    if (o < 128)      v = Wsrc[o * FIN + k];
    else if (o < 256) v = Wtgt[(o - 128) * FIN + k];
    else              v = Wres[(o - 256) * FIN + k];
    Wt[idx] = v;
}

// Fused proj: Linear -> LayerNorm(32) -> LeakyReLU for src/tgt, Linear+bias+Leaky for res.
// U_tgt emitted ONLY as bf16, twice: tT[bh][d][n] (agg B-operand) and
// tP[bh][d2][n] (escore t-columns, d-pairs packed in u32).
__global__ __launch_bounds__(NOUT) void proj_kernel(
    const float* __restrict__ x, const float* __restrict__ Wt,
    const float* __restrict__ gsrc, const float* __restrict__ bsrc,
    const float* __restrict__ gtgt, const float* __restrict__ btgt,
    const float* __restrict__ bres,
    float* __restrict__ Usrc, float* __restrict__ res,
    unsigned short* __restrict__ tT, unsigned* __restrict__ tP)
{
    __shared__ float xs[MT * FIN];
    int tid = threadIdx.x;
    int r0 = blockIdx.x * MT;              // row over flattened [B*N]
    const float* base = x + (size_t)r0 * FIN;
    for (int idx = tid; idx < MT * FIN; idx += NOUT) xs[idx] = base[idx];
    __syncthreads();

    int o = tid;
    float acc[MT];
    #pragma unroll
    for (int m = 0; m < MT; m++) acc[m] = 0.f;
    for (int k = 0; k < FIN; k++) {
        float w = Wt[k * NOUT + o];
        #pragma unroll
        for (int m = 0; m < MT; m++) acc[m] = fmaf(w, xs[m * FIN + k], acc[m]);
    }

    float gg = 1.f, bb2 = 0.f, bres_v = 0.f;
    if (o < 128)      { gg = gsrc[o];       bb2 = bsrc[o]; }
    else if (o < 256) { gg = gtgt[o - 128]; bb2 = btgt[o - 128]; }
    else              { bres_v = bres[o - 256]; }

    unsigned bfall[MT];
    unsigned tpack[4];
    #pragma unroll
    for (int m = 0; m < MT; m++) {
        int r = r0 + m;
        int b = r >> 9;            // /512
        int n = r & (NN - 1);
        float v = acc[m];
        if (o < 256) {
            float s = v, sq = v * v;
            #pragma unroll
            for (int msk = 16; msk >= 1; msk >>= 1) {
                s  += __shfl_xor(s,  msk);
                sq += __shfl_xor(sq, msk);
            }
            float mean = s * (1.f / DD);
            float var  = sq * (1.f / DD) - mean * mean;
            float nv = (v - mean) * rsqrtf(var + LN_EPS);
            nv = leaky(nv * gg + bb2);
            int oo = o & 127;
            int hh = oo >> 5, d = oo & 31;
            if (o < 128) {
                Usrc[((size_t)(b * HH + hh) * NN + n) * DD + d] = nv;
            } else {
                unsigned bf = f2bf(nv);
                bfall[m] = bf;
                if (m & 1) tpack[m >> 1] |= bf << 16; else tpack[m >> 1] = bf;
            }
        } else {
            res[(size_t)r * HID + (o - 256)] = leaky(v + bres_v);
        }
    }
    if (o >= 128 && o < 256) {
        int oo = o & 127, hh = oo >> 5, d = oo & 31;
        int b = r0 >> 9, n0 = r0 & (NN - 1);
        size_t off = ((size_t)(b * HH + hh) * DD + d) * NN + n0;   // n0 % 8 == 0
        *(uint4*)(tT + off) = make_uint4(tpack[0], tpack[1], tpack[2], tpack[3]);
        // d-pair packing for escore: lanes d, d^1 are adjacent in the wave
        unsigned pd[MT];
        #pragma unroll
        for (int m = 0; m < MT; m++) {
            unsigned prt = (unsigned)__shfl_xor((int)bfall[m], 1);
            pd[m] = bfall[m] | (prt << 16);          // valid on even-d lanes
        }
        if ((d & 1) == 0) {
            size_t offp = ((size_t)(b * HH + hh) * 16 + (d >> 1)) * NN + n0;
            *(uint4*)(tP + offp)     = make_uint4(pd[0], pd[1], pd[2], pd[3]);
            *(uint4*)(tP + offp + 4) = make_uint4(pd[4], pd[5], pd[6], pd[7]);
        }
    }
}

// e+softmax kernel, v4: 256-thread blocks, one j-half per block, 8 i-rows.
// Thread owns one t column (16 packed bf16x2 u32 regs, register-resident).
// launch_bounds(256,4): VGPR cap 128, live ~56 -> NO spills (r9's (256,6)->VGPR40
// spilled everything; r8's 512thr/VGPR128 capped residency at 1 block/CU).
// Writes UNNORMALIZED p (bf16) + per-64-j-chunk row sums; agg divides later.
// Row term dropped (softmax shift-inv); no max pass (|e| <~ 25, fp32-exp safe).
__global__ __launch_bounds__(256, 4) void escore_kernel(
    const float* __restrict__ Usrc, const unsigned* __restrict__ tP,
    const float* __restrict__ attn, unsigned short* __restrict__ pOut,
    float* __restrict__ rsum)
{
    __shared__ float s_lds[8][DD];     // 1KB

    const int tid = threadIdx.x;
    const int blk = blockIdx.x;        // grid 2048: bh(4b) | it(6b) | jh(1b)
    const int jh = blk & 1;
    const int it = (blk >> 1) & 63;
    const int bh = blk >> 7;

    const int j = jh * 256 + tid;
    const unsigned* tcol = tP + (size_t)bh * 16 * NN + j;     // coalesced u32 cols
    const float* srcU = Usrc + (size_t)bh * NN * DD + (size_t)(it * 8) * DD;
    const float* aU   = attn + (bh & 3) * DD;                 // uniform -> s_load

    unsigned tpk[16];
    #pragma unroll
    for (int d2 = 0; d2 < 16; d2++) tpk[d2] = tcol[d2 * NN];

    if (tid < 64) ((float4*)s_lds)[tid] = ((const float4*)srcU)[tid];
    __syncthreads();

    float At = 0.f, acc[8];
    #pragma unroll
    for (int r = 0; r < 8; r++) acc[r] = 0.f;

    #pragma unroll
    for (int dg = 0; dg < 8; dg++) {                // quad of d = [4dg, 4dg+4)
        const float a0 = aU[dg*4+0], a1 = aU[dg*4+1], a2 = aU[dg*4+2], a3 = aU[dg*4+3];
        const float t0 = bflo(tpk[dg*2]),   t1 = bfhi(tpk[dg*2]);
        const float t2 = bflo(tpk[dg*2+1]), t3 = bfhi(tpk[dg*2+1]);
        At = fmaf(a0, t0, fmaf(a1, t1, fmaf(a2, t2, fmaf(a3, t3, At))));
        #pragma unroll
        for (int r = 0; r < 8; r++) {
            float4 sv = *(float4*)&s_lds[r][dg * 4];
            acc[r] = fmaf(a0, fabsf(sv.x + t0), acc[r]);
            acc[r] = fmaf(a1, fabsf(sv.y + t1), acc[r]);
            acc[r] = fmaf(a2, fabsf(sv.z + t2), acc[r]);
            acc[r] = fmaf(a3, fabsf(sv.w + t3), acc[r]);
        }
    }

    const float cAt = 0.6f * SCALE * At;
    const int lane = tid & 63;
    const int chunk = jh * 4 + (tid >> 6);          // j-chunk of 64: 0..7
    unsigned short* pRow = pOut + ((size_t)bh * NN + it * 8) * NN + j;
    float* rs = rsum + ((size_t)bh * NN + it * 8) * 8 + chunk;

    #pragma unroll
    for (int r = 0; r < 8; r++) {
        float p = __expf(fmaf(0.4f * SCALE, acc[r], cAt));   // unnormalized
        float s = p;
        #pragma unroll
        for (int msk = 32; msk >= 1; msk >>= 1) s += __shfl_xor(s, msk);
        if (lane == 0) rs[(size_t)r * 8] = s;
        pRow[(size_t)r * NN] = (unsigned short)f2bf(p);
    }
}

// agg: batched MFMA GEMM  out[bh] = p~[bh] (512x512) @ tT[bh] (32x512, k-contig),
// normalized by rowsum (sum of 8 chunk partials) + residual + ReLU.
__global__ __launch_bounds__(256) void agg_kernel(
    const unsigned short* __restrict__ pM, const unsigned short* __restrict__ tT,
    const float* __restrict__ rsum, const float* __restrict__ res,
    float* __restrict__ out)
{
    const int tid = threadIdx.x, l = tid & 63;
    const int gw = blockIdx.x * 4 + (tid >> 6);   // 0..511
    const int bh = gw >> 5, mt = gw & 31;
    const int b = bh >> 2, h = bh & 3;

    const unsigned short* pA = pM + (size_t)bh * NN * NN
                               + (size_t)(mt * 16 + (l & 15)) * NN + ((l >> 4) * 8);
    const unsigned short* pB = tT + (size_t)bh * DD * NN
                               + (size_t)(l & 15) * NN + ((l >> 4) * 8);

    f32x4 acc0 = {0.f, 0.f, 0.f, 0.f}, acc1 = {0.f, 0.f, 0.f, 0.f};
    #pragma unroll
    for (int kt = 0; kt < 16; kt++) {
        bf16x8 av = *(const bf16x8*)(pA + kt * 32);
        bf16x8 b0 = *(const bf16x8*)(pB + kt * 32);
        bf16x8 b1 = *(const bf16x8*)(pB + 16 * NN + kt * 32);
        acc0 = __builtin_amdgcn_mfma_f32_16x16x32_bf16(av, b0, acc0, 0, 0, 0);
        acc1 = __builtin_amdgcn_mfma_f32_16x16x32_bf16(av, b1, acc1, 0, 0, 0);
    }

    // C/D layout (m89): col = lane&15, row = (lane>>4)*4 + reg
    const int i0 = mt * 16 + (l >> 4) * 4;
    const int cc = l & 15;
    #pragma unroll
    for (int q = 0; q < 4; q++) {
        const int ri = i0 + q;
        const float* rsq = rsum + ((size_t)bh * NN + ri) * 8;
        float4 s0 = *(const float4*)rsq;
        float4 s1 = *(const float4*)(rsq + 4);
        float sum = ((s0.x + s0.y) + (s0.z + s0.w)) + ((s1.x + s1.y) + (s1.z + s1.w));
        float inv = 1.f / sum;
        size_t row = (size_t)b * NN + ri;
        size_t a0 = row * HID + h * DD + cc;
        out[a0]      = fmaxf(fmaf(acc0[q], inv, res[a0]),      0.f);
        out[a0 + 16] = fmaxf(fmaf(acc1[q], inv, res[a0 + 16]), 0.f);
    }
}

extern "C" void kernel_launch(void* const* d_in, const int* in_sizes, int n_in,
                              void* d_out, int out_size, void* d_ws, size_t ws_size,
                              hipStream_t stream) {
    const float* uf   = (const float*)d_in[0];
    const float* Wsrc = (const float*)d_in[1];
    const float* gsrc = (const float*)d_in[2];
    const float* bsrc = (const float*)d_in[3];
    const float* Wtgt = (const float*)d_in[4];
    const float* gtgt = (const float*)d_in[5];
    const float* btgt = (const float*)d_in[6];
    const float* attn = (const float*)d_in[7];
    const float* Wres = (const float*)d_in[8];
    const float* bres = (const float*)d_in[9];
    float* out = (float*)d_out;

    float* ws   = (float*)d_ws;
    float* Wt   = ws;                        // 49152 f
    float* Usrc = ws + 49152;                // 262144 f
    float* resb = Usrc + 262144;             // 262144 f
    unsigned short* tT = (unsigned short*)(resb + 262144);   // 262144 u16
    unsigned* tP = (unsigned*)(tT + 262144);                 // 131072 u32
    float* rsum = (float*)(tP + 131072);                     // 65536 f
    unsigned short* pM = (unsigned short*)(rsum + 65536);    // 16*512*512 u16 = 8 MB

    pack_w<<<(FIN * NOUT + 255) / 256, 256, 0, stream>>>(Wsrc, Wtgt, Wres, Wt);
    proj_kernel<<<(BB * NN) / MT, NOUT, 0, stream>>>(uf, Wt, gsrc, bsrc, gtgt, btgt,
                                                     bres, Usrc, resb, tT, tP);
    escore_kernel<<<BB * HH * (NN / 8) * 2, 256, 0, stream>>>(Usrc, tP, attn, pM, rsum);
    agg_kernel<<<128, 256, 0, stream>>>(pM, tT, rsum, resb, out);
}

// Round 11
// 67.103 us; speedup vs baseline: 2.9306x; 1.8753x over previous
//
#include <hip/hip_runtime.h>

#define BB 4
#define NN 512
#define FIN 128
#define HH 4
#define DD 32
#define HID 128
#define NOUT 384   // 128 src + 128 tgt + 128 res
#define MT 8
#define LN_EPS 1e-5f
#define NEG 0.2f
#define SCALE 0.17677669529663687f

typedef __attribute__((ext_vector_type(8))) short bf16x8;
typedef __attribute__((ext_vector_type(4))) float f32x4;

__device__ __forceinline__ float leaky(float x){ return x > 0.f ? x : NEG*x; }

// round-to-nearest-even fp32 -> bf16 (finite inputs)
__device__ __forceinline__ unsigned f2bf(float f){
    unsigned u = __float_as_uint(f);
    return (u + 0x7fffu + ((u >> 16) & 1u)) >> 16;
}
__device__ __forceinline__ float bflo(unsigned u){ return __uint_as_float(u << 16); }
__device__ __forceinline__ float bfhi(unsigned u){ return __uint_as_float(u & 0xffff0000u); }

// Pack Wt[k][o]: o in [0,128)=W_src rows, [128,256)=W_tgt rows, [256,384)=W_res rows
__global__ void pack_w(const float* __restrict__ Wsrc, const float* __restrict__ Wtgt,
                       const float* __restrict__ Wres, float* __restrict__ Wt) {
    int idx = blockIdx.x * 256 + threadIdx.x;
    if (idx >= FIN * NOUT) return;
    int k = idx / NOUT, o = idx % NOUT;
    float v;
    if (o < 128)      v = Wsrc[o * FIN + k];
    else if (o < 256) v = Wtgt[(o - 128) * FIN + k];
    else              v = Wres[(o - 256) * FIN + k];
    Wt[idx] = v;
}

// Fused proj: Linear -> LayerNorm(32) -> LeakyReLU for src/tgt, Linear+bias+Leaky for res.
// U_tgt emitted ONLY as bf16, twice: tT[bh][d][n] (agg B-operand) and
// tP[bh][d2][n] (escore t-columns, d-pairs packed in u32).
__global__ __launch_bounds__(NOUT) void proj_kernel(
    const float* __restrict__ x, const float* __restrict__ Wt,
    const float* __restrict__ gsrc, const float* __restrict__ bsrc,
    const float* __restrict__ gtgt, const float* __restrict__ btgt,
    const float* __restrict__ bres,
    float* __restrict__ Usrc, float* __restrict__ res,
    unsigned short* __restrict__ tT, unsigned* __restrict__ tP)
{
    __shared__ float xs[MT * FIN];
    int tid = threadIdx.x;
    int r0 = blockIdx.x * MT;              // row over flattened [B*N]
    const float* base = x + (size_t)r0 * FIN;
    for (int idx = tid; idx < MT * FIN; idx += NOUT) xs[idx] = base[idx];
    __syncthreads();

    int o = tid;
    float acc[MT];
    #pragma unroll
    for (int m = 0; m < MT; m++) acc[m] = 0.f;
    for (int k = 0; k < FIN; k++) {
        float w = Wt[k * NOUT + o];
        #pragma unroll
        for (int m = 0; m < MT; m++) acc[m] = fmaf(w, xs[m * FIN + k], acc[m]);
    }

    float gg = 1.f, bb2 = 0.f, bres_v = 0.f;
    if (o < 128)      { gg = gsrc[o];       bb2 = bsrc[o]; }
    else if (o < 256) { gg = gtgt[o - 128]; bb2 = btgt[o - 128]; }
    else              { bres_v = bres[o - 256]; }

    unsigned bfall[MT];
    unsigned tpack[4];
    #pragma unroll
    for (int m = 0; m < MT; m++) {
        int r = r0 + m;
        int b = r >> 9;            // /512
        int n = r & (NN - 1);
        float v = acc[m];
        if (o < 256) {
            float s = v, sq = v * v;
            #pragma unroll
            for (int msk = 16; msk >= 1; msk >>= 1) {
                s  += __shfl_xor(s,  msk);
                sq += __shfl_xor(sq, msk);
            }
            float mean = s * (1.f / DD);
            float var  = sq * (1.f / DD) - mean * mean;
            float nv = (v - mean) * rsqrtf(var + LN_EPS);
            nv = leaky(nv * gg + bb2);
            int oo = o & 127;
            int hh = oo >> 5, d = oo & 31;
            if (o < 128) {
                Usrc[((size_t)(b * HH + hh) * NN + n) * DD + d] = nv;
            } else {
                unsigned bf = f2bf(nv);
                bfall[m] = bf;
                if (m & 1) tpack[m >> 1] |= bf << 16; else tpack[m >> 1] = bf;
            }
        } else {
            res[(size_t)r * HID + (o - 256)] = leaky(v + bres_v);
        }
    }
    if (o >= 128 && o < 256) {
        int oo = o & 127, hh = oo >> 5, d = oo & 31;
        int b = r0 >> 9, n0 = r0 & (NN - 1);
        size_t off = ((size_t)(b * HH + hh) * DD + d) * NN + n0;   // n0 % 8 == 0
        *(uint4*)(tT + off) = make_uint4(tpack[0], tpack[1], tpack[2], tpack[3]);
        // d-pair packing for escore: lanes d, d^1 are adjacent in the wave
        unsigned pd[MT];
        #pragma unroll
        for (int m = 0; m < MT; m++) {
            unsigned prt = (unsigned)__shfl_xor((int)bfall[m], 1);
            pd[m] = bfall[m] | (prt << 16);          // valid on even-d lanes
        }
        if ((d & 1) == 0) {
            size_t offp = ((size_t)(b * HH + hh) * 16 + (d >> 1)) * NN + n0;
            *(uint4*)(tP + offp)     = make_uint4(pd[0], pd[1], pd[2], pd[3]);
            *(uint4*)(tP + offp + 4) = make_uint4(pd[4], pd[5], pd[6], pd[7]);
        }
    }
}

// e+softmax v5 (persistent tiles): 512 blocks x 256 thr. Block = (bh, jh) x 4 i-tiles.
// t-columns (tpk[16]) and attn row loaded ONCE per block, reused across 4 tiles;
// s double-buffered in LDS with register prefetch (1 barrier/tile). At hoisted
// (it-invariant). NO launch_bounds min-waves: r9/r10 proved any cap => allocator
// spills catastrophically (VGPR 40/64, 300+ MB scratch traffic).
// Writes UNNORMALIZED p (bf16) + per-64-j-chunk row sums; agg divides later.
// Row term dropped (softmax shift-inv); no max pass (|e| <~ 25, fp32-exp safe).
__global__ __launch_bounds__(256) void escore_kernel(
    const float* __restrict__ Usrc, const unsigned* __restrict__ tP,
    const float* __restrict__ attn, unsigned short* __restrict__ pOut,
    float* __restrict__ rsum)
{
    __shared__ float s_lds[2][8][DD];  // 2KB double buffer
    __shared__ float a_lds[DD];

    const int tid = threadIdx.x;
    const int blk = blockIdx.x;        // 512 blocks: bh(4b) | itg(4b) | jh(1b)
    const int jh  = blk & 1;
    const int itg = (blk >> 1) & 15;
    const int bh  = blk >> 5;

    const int j = jh * 256 + tid;
    const unsigned* tcol = tP + (size_t)bh * 16 * NN + j;     // coalesced u32 cols
    const float* srcBase = Usrc + (size_t)bh * NN * DD + (size_t)(itg * 4 * 8) * DD;

    if (tid < DD) a_lds[tid] = attn[(bh & 3) * DD + tid];

    unsigned tpk[16];
    #pragma unroll
    for (int d2 = 0; d2 < 16; d2++) tpk[d2] = tcol[d2 * NN];

    float4 sp;                                                 // s prefetch (tile 0)
    if (tid < 64) sp = ((const float4*)srcBase)[tid];
    __syncthreads();                                           // a_lds ready

    // At = <a, t_j>, it-invariant -> once per block
    float At = 0.f;
    #pragma unroll
    for (int dg = 0; dg < 8; dg++) {
        const float a0 = a_lds[dg*4+0], a1 = a_lds[dg*4+1],
                    a2 = a_lds[dg*4+2], a3 = a_lds[dg*4+3];
        const float t0 = bflo(tpk[dg*2]),   t1 = bfhi(tpk[dg*2]);
        const float t2 = bflo(tpk[dg*2+1]), t3 = bfhi(tpk[dg*2+1]);
        At = fmaf(a0, t0, fmaf(a1, t1, fmaf(a2, t2, fmaf(a3, t3, At))));
    }
    const float cAt = 0.6f * SCALE * At;
    const int lane = tid & 63;
    const int chunk = jh * 4 + (tid >> 6);          // j-chunk of 64: 0..7

    for (int k = 0; k < 4; k++) {
        const int cur = k & 1;
        if (tid < 64) ((float4*)s_lds[cur])[tid] = sp;
        __syncthreads();                            // s[cur] ready (prev buf free)
        if (k < 3 && tid < 64) sp = ((const float4*)(srcBase + (k + 1) * 8 * DD))[tid];

        float acc[8];
        #pragma unroll
        for (int r = 0; r < 8; r++) acc[r] = 0.f;

        #pragma unroll
        for (int dg = 0; dg < 8; dg++) {            // quad of d = [4dg, 4dg+4)
            const float a0 = a_lds[dg*4+0], a1 = a_lds[dg*4+1],
                        a2 = a_lds[dg*4+2], a3 = a_lds[dg*4+3];
            const float t0 = bflo(tpk[dg*2]),   t1 = bfhi(tpk[dg*2]);
            const float t2 = bflo(tpk[dg*2+1]), t3 = bfhi(tpk[dg*2+1]);
            #pragma unroll
            for (int r = 0; r < 8; r++) {
                float4 sv = *(float4*)&s_lds[cur][r][dg * 4];
                acc[r] = fmaf(a0, fabsf(sv.x + t0), acc[r]);
                acc[r] = fmaf(a1, fabsf(sv.y + t1), acc[r]);
                acc[r] = fmaf(a2, fabsf(sv.z + t2), acc[r]);
                acc[r] = fmaf(a3, fabsf(sv.w + t3), acc[r]);
            }
        }

        const int it = itg * 4 + k;
        unsigned short* pRow = pOut + ((size_t)bh * NN + it * 8) * NN + j;
        float* rs = rsum + ((size_t)bh * NN + it * 8) * 8 + chunk;
        #pragma unroll
        for (int r = 0; r < 8; r++) {
            float p = __expf(fmaf(0.4f * SCALE, acc[r], cAt));   // unnormalized
            float s = p;
            #pragma unroll
            for (int msk = 32; msk >= 1; msk >>= 1) s += __shfl_xor(s, msk);
            if (lane == 0) rs[(size_t)r * 8] = s;
            pRow[(size_t)r * NN] = (unsigned short)f2bf(p);
        }
    }
}

// agg: batched MFMA GEMM  out[bh] = p~[bh] (512x512) @ tT[bh] (32x512, k-contig),
// normalized by rowsum (sum of 8 chunk partials) + residual + ReLU.
__global__ __launch_bounds__(256) void agg_kernel(
    const unsigned short* __restrict__ pM, const unsigned short* __restrict__ tT,
    const float* __restrict__ rsum, const float* __restrict__ res,
    float* __restrict__ out)
{
    const int tid = threadIdx.x, l = tid & 63;
    const int gw = blockIdx.x * 4 + (tid >> 6);   // 0..511
    const int bh = gw >> 5, mt = gw & 31;
    const int b = bh >> 2, h = bh & 3;

    const unsigned short* pA = pM + (size_t)bh * NN * NN
                               + (size_t)(mt * 16 + (l & 15)) * NN + ((l >> 4) * 8);
    const unsigned short* pB = tT + (size_t)bh * DD * NN
                               + (size_t)(l & 15) * NN + ((l >> 4) * 8);

    f32x4 acc0 = {0.f, 0.f, 0.f, 0.f}, acc1 = {0.f, 0.f, 0.f, 0.f};
    #pragma unroll
    for (int kt = 0; kt < 16; kt++) {
        bf16x8 av = *(const bf16x8*)(pA + kt * 32);
        bf16x8 b0 = *(const bf16x8*)(pB + kt * 32);
        bf16x8 b1 = *(const bf16x8*)(pB + 16 * NN + kt * 32);
        acc0 = __builtin_amdgcn_mfma_f32_16x16x32_bf16(av, b0, acc0, 0, 0, 0);
        acc1 = __builtin_amdgcn_mfma_f32_16x16x32_bf16(av, b1, acc1, 0, 0, 0);
    }

    // C/D layout (m89): col = lane&15, row = (lane>>4)*4 + reg
    const int i0 = mt * 16 + (l >> 4) * 4;
    const int cc = l & 15;
    #pragma unroll
    for (int q = 0; q < 4; q++) {
        const int ri = i0 + q;
        const float* rsq = rsum + ((size_t)bh * NN + ri) * 8;
        float4 s0 = *(const float4*)rsq;
        float4 s1 = *(const float4*)(rsq + 4);
        float sum = ((s0.x + s0.y) + (s0.z + s0.w)) + ((s1.x + s1.y) + (s1.z + s1.w));
        float inv = 1.f / sum;
        size_t row = (size_t)b * NN + ri;
        size_t a0 = row * HID + h * DD + cc;
        out[a0]      = fmaxf(fmaf(acc0[q], inv, res[a0]),      0.f);
        out[a0 + 16] = fmaxf(fmaf(acc1[q], inv, res[a0 + 16]), 0.f);
    }
}

extern "C" void kernel_launch(void* const* d_in, const int* in_sizes, int n_in,
                              void* d_out, int out_size, void* d_ws, size_t ws_size,
                              hipStream_t stream) {
    const float* uf   = (const float*)d_in[0];
    const float* Wsrc = (const float*)d_in[1];
    const float* gsrc = (const float*)d_in[2];
    const float* bsrc = (const float*)d_in[3];
    const float* Wtgt = (const float*)d_in[4];
    const float* gtgt = (const float*)d_in[5];
    const float* btgt = (const float*)d_in[6];
    const float* attn = (const float*)d_in[7];
    const float* Wres = (const float*)d_in[8];
    const float* bres = (const float*)d_in[9];
    float* out = (float*)d_out;

    float* ws   = (float*)d_ws;
    float* Wt   = ws;                        // 49152 f
    float* Usrc = ws + 49152;                // 262144 f
    float* resb = Usrc + 262144;             // 262144 f
    unsigned short* tT = (unsigned short*)(resb + 262144);   // 262144 u16
    unsigned* tP = (unsigned*)(tT + 262144);                 // 131072 u32
    float* rsum = (float*)(tP + 131072);                     // 65536 f
    unsigned short* pM = (unsigned short*)(rsum + 65536);    // 16*512*512 u16 = 8 MB

    pack_w<<<(FIN * NOUT + 255) / 256, 256, 0, stream>>>(Wsrc, Wtgt, Wres, Wt);
    proj_kernel<<<(BB * NN) / MT, NOUT, 0, stream>>>(uf, Wt, gsrc, bsrc, gtgt, btgt,
                                                     bres, Usrc, resb, tT, tP);
    escore_kernel<<<512, 256, 0, stream>>>(Usrc, tP, attn, pM, rsum);
    agg_kernel<<<128, 256, 0, stream>>>(pM, tT, rsum, resb, out);
}

// Round 12
// 57.669 us; speedup vs baseline: 3.4100x; 1.1636x over previous
//
#include <hip/hip_runtime.h>

#define BB 4
#define NN 512
#define FIN 128
#define HH 4
#define DD 32
#define HID 128
#define NOUT 384   // 128 src + 128 tgt + 128 res
#define MT 8
#define LN_EPS 1e-5f
#define NEG 0.2f
#define SCALE 0.17677669529663687f

typedef __attribute__((ext_vector_type(8))) short bf16x8;
typedef __attribute__((ext_vector_type(4))) float f32x4;

__device__ __forceinline__ float leaky(float x){ return x > 0.f ? x : NEG*x; }

// round-to-nearest-even fp32 -> bf16 (finite inputs)
__device__ __forceinline__ unsigned f2bf(float f){
    unsigned u = __float_as_uint(f);
    return (u + 0x7fffu + ((u >> 16) & 1u)) >> 16;
}

// Pack Wt[k][o]: o in [0,128)=W_src rows, [128,256)=W_tgt rows, [256,384)=W_res rows
__global__ void pack_w(const float* __restrict__ Wsrc, const float* __restrict__ Wtgt,
                       const float* __restrict__ Wres, float* __restrict__ Wt) {
    int idx = blockIdx.x * 256 + threadIdx.x;
    if (idx >= FIN * NOUT) return;
    int k = idx / NOUT, o = idx % NOUT;
    float v;
    if (o < 128)      v = Wsrc[o * FIN + k];
    else if (o < 256) v = Wtgt[(o - 128) * FIN + k];
    else              v = Wres[(o - 256) * FIN + k];
    Wt[idx] = v;
}

// Fused proj: Linear -> LayerNorm(32) -> LeakyReLU for src/tgt, Linear+bias+Leaky for res.
// U_tgt emitted ONLY transposed: fp32 tTf[bh][d][n] (escore t-columns, coalesced)
// and bf16 tT[bh][d][n] (MFMA agg B-operand).
__global__ __launch_bounds__(NOUT) void proj_kernel(
    const float* __restrict__ x, const float* __restrict__ Wt,
    const float* __restrict__ gsrc, const float* __restrict__ bsrc,
    const float* __restrict__ gtgt, const float* __restrict__ btgt,
    const float* __restrict__ bres,
    float* __restrict__ Usrc, float* __restrict__ res,
    float* __restrict__ tTf, unsigned short* __restrict__ tT)
{
    __shared__ float xs[MT * FIN];
    int tid = threadIdx.x;
    int r0 = blockIdx.x * MT;              // row over flattened [B*N]
    const float* base = x + (size_t)r0 * FIN;
    for (int idx = tid; idx < MT * FIN; idx += NOUT) xs[idx] = base[idx];
    __syncthreads();

    int o = tid;
    float acc[MT];
    #pragma unroll
    for (int m = 0; m < MT; m++) acc[m] = 0.f;
    for (int k = 0; k < FIN; k++) {
        float w = Wt[k * NOUT + o];
        #pragma unroll
        for (int m = 0; m < MT; m++) acc[m] = fmaf(w, xs[m * FIN + k], acc[m]);
    }

    float gg = 1.f, bb2 = 0.f, bres_v = 0.f;
    if (o < 128)      { gg = gsrc[o];       bb2 = bsrc[o]; }
    else if (o < 256) { gg = gtgt[o - 128]; bb2 = btgt[o - 128]; }
    else              { bres_v = bres[o - 256]; }

    float tf[MT];
    unsigned tpack[4];
    #pragma unroll
    for (int m = 0; m < MT; m++) {
        int r = r0 + m;
        int b = r >> 9;            // /512
        int n = r & (NN - 1);
        float v = acc[m];
        if (o < 256) {
            float s = v, sq = v * v;
            #pragma unroll
            for (int msk = 16; msk >= 1; msk >>= 1) {
                s  += __shfl_xor(s,  msk);
                sq += __shfl_xor(sq, msk);
            }
            float mean = s * (1.f / DD);
            float var  = sq * (1.f / DD) - mean * mean;
            float nv = (v - mean) * rsqrtf(var + LN_EPS);
            nv = leaky(nv * gg + bb2);
            int oo = o & 127;
            int hh = oo >> 5, d = oo & 31;
            if (o < 128) {
                Usrc[((size_t)(b * HH + hh) * NN + n) * DD + d] = nv;
            } else {
                tf[m] = nv;
                unsigned bf = f2bf(nv);
                if (m & 1) tpack[m >> 1] |= bf << 16; else tpack[m >> 1] = bf;
            }
        } else {
            res[(size_t)r * HID + (o - 256)] = leaky(v + bres_v);
        }
    }
    if (o >= 128 && o < 256) {
        int oo = o & 127, hh = oo >> 5, d = oo & 31;
        int b = r0 >> 9, n0 = r0 & (NN - 1);
        size_t off = ((size_t)(b * HH + hh) * DD + d) * NN + n0;   // n0 % 8 == 0
        *(float4*)(tTf + off)     = make_float4(tf[0], tf[1], tf[2], tf[3]);
        *(float4*)(tTf + off + 4) = make_float4(tf[4], tf[5], tf[6], tf[7]);
        *(uint4*)(tT + off) = make_uint4(tpack[0], tpack[1], tpack[2], tpack[3]);
    }
}

// e+softmax v6: ZERO LDS, zero barriers. 1024 blocks x 256 thr (4 waves).
// Thread owns t column j (32 fp32 VGPRs, coalesced load from tTf); a in VGPRs;
// s rows via WAVE-UNIFORM loads (scalar-cache broadcast path, no DS pipe).
// Inner loop = v_add + v_fma(abs) only. 2 i-tiles/block amortize t/a loads.
// Writes UNNORMALIZED p (bf16) + per-64-j-chunk row sums; agg divides later.
// Row term dropped (softmax shift-inv); no max pass (|e| <~ 25, fp32-exp safe).
__global__ __launch_bounds__(256) void escore_kernel(
    const float* __restrict__ Usrc, const float* __restrict__ tTf,
    const float* __restrict__ attn, unsigned short* __restrict__ pOut,
    float* __restrict__ rsum)
{
    const int tid = threadIdx.x;
    const int blk = blockIdx.x;        // 1024 blocks: bh(4b) | itg(5b) | jh(1b)
    const int jh  = blk & 1;
    const int itg = (blk >> 1) & 31;   // 32 groups of 2 i-tiles
    const int bh  = blk >> 6;

    const int j = jh * 256 + tid;
    const float* tcol = tTf + (size_t)bh * DD * NN + j;        // coalesced columns
    const float* srcB = Usrc + (size_t)bh * NN * DD + (size_t)(itg * 16) * DD;
    const float* aP   = attn + (bh & 3) * DD;

    float t[DD];
    #pragma unroll
    for (int d = 0; d < DD; d++) t[d] = tcol[d * NN];

    float a[DD];
    #pragma unroll
    for (int q = 0; q < 8; q++) {
        float4 v = *(const float4*)(aP + q * 4);
        a[q*4+0] = v.x; a[q*4+1] = v.y; a[q*4+2] = v.z; a[q*4+3] = v.w;
    }

    float At = 0.f;
    #pragma unroll
    for (int d = 0; d < DD; d++) At = fmaf(a[d], t[d], At);
    const float cAt = 0.6f * SCALE * At;

    const int lane = tid & 63;
    const int chunk = jh * 4 + (tid >> 6);          // j-chunk of 64: 0..7

    #pragma unroll
    for (int k = 0; k < 2; k++) {
        const float* sT = srcB + k * 8 * DD;        // uniform base for this tile
        float acc[8];
        #pragma unroll
        for (int r = 0; r < 8; r++) acc[r] = 0.f;

        #pragma unroll
        for (int r = 0; r < 8; r++) {
            const float* srow = sT + r * DD;        // wave-uniform address
            #pragma unroll
            for (int d = 0; d < DD; d++)
                acc[r] = fmaf(a[d], fabsf(srow[d] + t[d]), acc[r]);
        }

        const int it = itg * 2 + k;
        unsigned short* pRow = pOut + ((size_t)bh * NN + it * 8) * NN + j;
        float* rs = rsum + ((size_t)bh * NN + it * 8) * 8 + chunk;
        #pragma unroll
        for (int r = 0; r < 8; r++) {
            float p = __expf(fmaf(0.4f * SCALE, acc[r], cAt));   // unnormalized
            float s = p;
            #pragma unroll
            for (int msk = 32; msk >= 1; msk >>= 1) s += __shfl_xor(s, msk);
            if (lane == 0) rs[(size_t)r * 8] = s;
            pRow[(size_t)r * NN] = (unsigned short)f2bf(p);
        }
    }
}

// agg: batched MFMA GEMM  out[bh] = p~[bh] (512x512) @ tT[bh] (32x512, k-contig),
// normalized by rowsum (sum of 8 chunk partials) + residual + ReLU.
__global__ __launch_bounds__(256) void agg_kernel(
    const unsigned short* __restrict__ pM, const unsigned short* __restrict__ tT,
    const float* __restrict__ rsum, const float* __restrict__ res,
    float* __restrict__ out)
{
    const int tid = threadIdx.x, l = tid & 63;
    const int gw = blockIdx.x * 4 + (tid >> 6);   // 0..511
    const int bh = gw >> 5, mt = gw & 31;
    const int b = bh >> 2, h = bh & 3;

    const unsigned short* pA = pM + (size_t)bh * NN * NN
                               + (size_t)(mt * 16 + (l & 15)) * NN + ((l >> 4) * 8);
    const unsigned short* pB = tT + (size_t)bh * DD * NN
                               + (size_t)(l & 15) * NN + ((l >> 4) * 8);

    f32x4 acc0 = {0.f, 0.f, 0.f, 0.f}, acc1 = {0.f, 0.f, 0.f, 0.f};
    #pragma unroll
    for (int kt = 0; kt < 16; kt++) {
        bf16x8 av = *(const bf16x8*)(pA + kt * 32);
        bf16x8 b0 = *(const bf16x8*)(pB + kt * 32);
        bf16x8 b1 = *(const bf16x8*)(pB + 16 * NN + kt * 32);
        acc0 = __builtin_amdgcn_mfma_f32_16x16x32_bf16(av, b0, acc0, 0, 0, 0);
        acc1 = __builtin_amdgcn_mfma_f32_16x16x32_bf16(av, b1, acc1, 0, 0, 0);
    }

    // C/D layout (m89): col = lane&15, row = (lane>>4)*4 + reg
    const int i0 = mt * 16 + (l >> 4) * 4;
    const int cc = l & 15;
    #pragma unroll
    for (int q = 0; q < 4; q++) {
        const int ri = i0 + q;
        const float* rsq = rsum + ((size_t)bh * NN + ri) * 8;
        float4 s0 = *(const float4*)rsq;
        float4 s1 = *(const float4*)(rsq + 4);
        float sum = ((s0.x + s0.y) + (s0.z + s0.w)) + ((s1.x + s1.y) + (s1.z + s1.w));
        float inv = 1.f / sum;
        size_t row = (size_t)b * NN + ri;
        size_t a0 = row * HID + h * DD + cc;
        out[a0]      = fmaxf(fmaf(acc0[q], inv, res[a0]),      0.f);
        out[a0 + 16] = fmaxf(fmaf(acc1[q], inv, res[a0 + 16]), 0.f);
    }
}

extern "C" void kernel_launch(void* const* d_in, const int* in_sizes, int n_in,
                              void* d_out, int out_size, void* d_ws, size_t ws_size,
                              hipStream_t stream) {
    const float* uf   = (const float*)d_in[0];
    const float* Wsrc = (const float*)d_in[1];
    const float* gsrc = (const float*)d_in[2];
    const float* bsrc = (const float*)d_in[3];
    const float* Wtgt = (const float*)d_in[4];
    const float* gtgt = (const float*)d_in[5];
    const float* btgt = (const float*)d_in[6];
    const float* attn = (const float*)d_in[7];
    const float* Wres = (const float*)d_in[8];
    const float* bres = (const float*)d_in[9];
    float* out = (float*)d_out;

    float* ws   = (float*)d_ws;
    float* Wt   = ws;                        // 49152 f
    float* Usrc = ws + 49152;                // 262144 f
    float* resb = Usrc + 262144;             // 262144 f
    float* tTf  = resb + 262144;             // 262144 f (fp32 transposed U_tgt)
    unsigned short* tT = (unsigned short*)(tTf + 262144);    // 262144 u16
    float* rsum = (float*)(tT + 262144);                     // 65536 f
    unsigned short* pM = (unsigned short*)(rsum + 65536);    // 16*512*512 u16 = 8 MB

    pack_w<<<(FIN * NOUT + 255) / 256, 256, 0, stream>>>(Wsrc, Wtgt, Wres, Wt);
    proj_kernel<<<(BB * NN) / MT, NOUT, 0, stream>>>(uf, Wt, gsrc, bsrc, gtgt, btgt,
                                                     bres, Usrc, resb, tTf, tT);
    escore_kernel<<<1024, 256, 0, stream>>>(Usrc, tTf, attn, pM, rsum);
    agg_kernel<<<128, 256, 0, stream>>>(pM, tT, rsum, resb, out);
}